// Round 2
// baseline (546.389 us; speedup 1.0000x reference)
//
#include <hip/hip_runtime.h>

// ShapeContext: weight is eye(NOUT) by construction (identity sparse-conv),
// so out[n, k*NIN + i] = (rules[k,n] < N ? features[rules[k,n], i] : 0) + bias[k*NIN+i].
// Pure gather -> memory-bound.
//
// R5: deduced from rocprof that the gather kernel is <284us (absent from the
// top-5, which are all ~289us poison fills folded into dur_us) -> real kernel
// ~245us. Store-pattern change (R4) was neutral -> READ-side bound: 453MB of
// random 128B feature rows, ~0% L1 hit, ~24% L2 hit. Per-CU demand is only
// ~3B/cy, so the stall is downstream queueing -- suspect: L1 miss-queue depth
// serializing the all-miss gather stream (caps random reads at ~2TB/s).
//
// Change: feature loads via inline-asm `global_load_dwordx4 ... sc0 nt`:
//   sc0 = device-scope -> bypass the (useless, 0%-hit) L1 and its MSHR queue;
//   nt  = non-temporal -> don't evict rules/bias lines from L2 on the way.
// rules/bias keep normal cached loads (real L1/L2 locality). Stores stay
// non-temporal + perfectly linear (n-major, out_f4[tid]).

#define N_SITES 131072   // 2^17
#define NIN 32
#define FV 27
#define NOUT 864         // FV * NIN
#define F4_PER_SITE 216  // NOUT / 4
#define TOTAL_F4 (N_SITES * (long long)F4_PER_SITE)  // 28,311,552 = 110592 * 256

typedef float f32x4 __attribute__((ext_vector_type(4)));

__global__ __launch_bounds__(256) void shape_context_gather(
    const float* __restrict__ features,   // [N, NIN]
    const float* __restrict__ bias,       // [NOUT]
    const int*   __restrict__ rules,      // [FV, N]
    float*       __restrict__ out)        // [N, NOUT]
{
    unsigned tid = blockIdx.x * 256u + threadIdx.x;
    if (tid >= (unsigned)TOTAL_F4) return;      // grid divides exactly; safety

    unsigned n = tid / F4_PER_SITE;             // site (magic-mul division)
    unsigned j = tid - n * F4_PER_SITE;         // 0..215 within site
    unsigned k = j >> 3;                        // filter offset 0..26
    unsigned c = j & 7;                         // float4 within 32-ch row

    int r = rules[k * (unsigned)N_SITES + n];   // cached; 8 lanes broadcast

    bool valid = (unsigned)r < (unsigned)N_SITES;
    unsigned rr = valid ? (unsigned)r : 0u;     // branch-free clamp+mask

    // Gather one 16B chunk of the 128B feature row, bypassing L1 (sc0) and
    // marked streaming (nt). The s_waitcnt must live inside the asm block:
    // the compiler does not track hardware hazards for asm-produced values.
    // At this point the thread has no other loads it still needs in flight
    // (r already consumed; bias load is needed immediately after anyway).
    const f32x4* src = (const f32x4*)features + ((unsigned long long)rr * 8ull + c);
    f32x4 v;
    asm volatile("global_load_dwordx4 %0, %1, off sc0 nt\n\t"
                 "s_waitcnt vmcnt(0)"
                 : "=v"(v)
                 : "v"(src));
    if (!valid) v = (f32x4){0.f, 0.f, 0.f, 0.f};

    v += ((const f32x4*)bias)[j];               // 3.4KB, L1-resident

    __builtin_nontemporal_store(v, ((f32x4*)out) + tid);  // linear stream
}

extern "C" void kernel_launch(void* const* d_in, const int* in_sizes, int n_in,
                              void* d_out, int out_size, void* d_ws, size_t ws_size,
                              hipStream_t stream) {
    const float* features = (const float*)d_in[0];
    // d_in[1] = weight: eye(NOUT) by ShapeContext construction -> gather, not matmul
    const float* bias     = (const float*)d_in[2];
    const int*   rules    = (const int*)d_in[3];
    float*       out      = (float*)d_out;

    const long long total   = TOTAL_F4;
    const int       threads = 256;
    const int       blocks  = (int)((total + threads - 1) / threads);

    shape_context_gather<<<blocks, threads, 0, stream>>>(features, bias, rules, out);
}

// Round 3
// 511.615 us; speedup vs baseline: 1.0680x; 1.0680x over previous
//
#include <hip/hip_runtime.h>

// ShapeContext: weight is eye(NOUT) by construction (identity sparse-conv),
// so out[n, k*NIN + i] = (rules[k,n] < N ? features[rules[k,n], i] : 0) + bias[k*NIN+i].
// Pure gather -> memory-bound.
//
// R6: MLP expansion. History: store-pattern change (R4) neutral, L1-bypass
// (R5) neutral -> not path-bound. Arithmetic: 3.75 TB/s effective =
// 6.1 B/cy/CU; with 1 gather/thread and a serialized rules->gather->store
// chain, a wave holds ~1 outstanding 1KB gather -> Little's law ceiling with
// 32 waves/CU is exactly where we sit. Fix: 4 independent float4s per thread
// (base + {0,256,512,768}): 4 rules loads in flight, then 4 feature gathers
// in flight -> ~4x in-flight bytes per wave. Stores remain 4 contiguous
// wave-coalesced 1KB slabs (nontemporal, linear across the block's 1024 f4s).
// Plain cached loads for rules/features (features has 27x average reuse,
// ~24% L2 + LLC-resident).

#define N_SITES 131072   // 2^17
#define NIN 32
#define FV 27
#define NOUT 864         // FV * NIN
#define F4_PER_SITE 216  // NOUT / 4
#define TOTAL_F4 (N_SITES * (long long)F4_PER_SITE)  // 28,311,552 = 27,648 * 1024
#define ELEMS 4

typedef float f32x4 __attribute__((ext_vector_type(4)));

__global__ __launch_bounds__(256) void shape_context_gather(
    const float* __restrict__ features,   // [N, NIN]
    const float* __restrict__ bias,       // [NOUT]
    const int*   __restrict__ rules,      // [FV, N]
    float*       __restrict__ out)        // [N, NOUT]
{
    const unsigned base = blockIdx.x * (256u * ELEMS) + threadIdx.x;

    int      r[ELEMS];
    unsigned jj[ELEMS];
    f32x4    v[ELEMS];

    // Phase 1: issue all rules loads (independent -> all in flight at once).
    #pragma unroll
    for (int i = 0; i < ELEMS; ++i) {
        unsigned tid = base + i * 256u;
        unsigned n = tid / F4_PER_SITE;        // magic-mul division
        unsigned j = tid - n * F4_PER_SITE;    // 0..215
        unsigned k = j >> 3;                   // filter offset 0..26
        jj[i] = j;
        r[i] = rules[k * (unsigned)N_SITES + n];
    }

    // Phase 2: issue all feature gathers (compiler interleaves via counted
    // vmcnt: gather i issues as soon as r[i] lands) -> 4x MLP per wave.
    #pragma unroll
    for (int i = 0; i < ELEMS; ++i) {
        bool valid = (unsigned)r[i] < (unsigned)N_SITES;
        unsigned rr = valid ? (unsigned)r[i] : 0u;   // branch-free clamp+mask
        v[i] = ((const f32x4*)features)[rr * 8u + (jj[i] & 7u)];
        if (!valid) v[i] = (f32x4){0.f, 0.f, 0.f, 0.f};
    }

    // Phase 3: bias + linear nontemporal store (4 contiguous 1KB wave-slabs).
    #pragma unroll
    for (int i = 0; i < ELEMS; ++i) {
        f32x4 o = v[i] + ((const f32x4*)bias)[jj[i]];
        __builtin_nontemporal_store(o, ((f32x4*)out) + (base + i * 256u));
    }
}

extern "C" void kernel_launch(void* const* d_in, const int* in_sizes, int n_in,
                              void* d_out, int out_size, void* d_ws, size_t ws_size,
                              hipStream_t stream) {
    const float* features = (const float*)d_in[0];
    // d_in[1] = weight: eye(NOUT) by ShapeContext construction -> gather, not matmul
    const float* bias     = (const float*)d_in[2];
    const int*   rules    = (const int*)d_in[3];
    float*       out      = (float*)d_out;

    const long long total   = TOTAL_F4;
    const int       threads = 256;
    const int       blocks  = (int)(total / (threads * ELEMS));  // 27,648 exact

    shape_context_gather<<<blocks, threads, 0, stream>>>(features, bias, rules, out);
}